// Round 8
// baseline (203.705 us; speedup 1.0000x reference)
//
#include <hip/hip_runtime.h>
#include <hip/hip_bf16.h>

typedef __attribute__((ext_vector_type(4))) int i32x4;
typedef __attribute__((ext_vector_type(16))) int i32x16;

#define M_DIM 8192
#define N_DIM 8192
#define K_DIM 2048
#define BK 128                   // i8 K-bytes per K-tile (4 ks-slices of K=32)
#define WCOUNT (N_DIM * K_DIM)

// ---------------- kernel 1: per-block partial sums of |w| ----------------
__global__ __launch_bounds__(256) void k_abs_partial(const float* __restrict__ w,
                                                     float* __restrict__ part) {
    int tid = blockIdx.x * 256 + threadIdx.x;
    const float4* w4 = (const float4*)w;
    float s = 0.0f;
    const int total4 = WCOUNT / 4;
    for (int i = tid; i < total4; i += 2048 * 256) {
        float4 v = w4[i];
        s += fabsf(v.x) + fabsf(v.y) + fabsf(v.z) + fabsf(v.w);
    }
    #pragma unroll
    for (int off = 1; off < 64; off <<= 1) s += __shfl_xor(s, off);
    __shared__ float red[4];
    if ((threadIdx.x & 63) == 0) red[threadIdx.x >> 6] = s;
    __syncthreads();
    if (threadIdx.x == 0)
        part[blockIdx.x] = (red[0] + red[1]) + (red[2] + red[3]);
}

// ---------------- kernel 2: deterministic final reduce -> sum|w| ----------------
__global__ __launch_bounds__(256) void k_abs_final(const float* __restrict__ part,
                                                   float* __restrict__ sum) {
    int t = threadIdx.x;
    float s = 0.0f;
    #pragma unroll
    for (int i = 0; i < 8; i++) s += part[t + i * 256];
    #pragma unroll
    for (int off = 1; off < 64; off <<= 1) s += __shfl_xor(s, off);
    __shared__ float red[4];
    if ((t & 63) == 0) red[t >> 6] = s;
    __syncthreads();
    if (t == 0) sum[0] = (red[0] + red[1]) + (red[2] + red[3]);
}

// ---------------- kernel 3: ternary weight quant -> int8 {-1,0,1} ----------------
__global__ __launch_bounds__(256) void k_wquant(const float* __restrict__ w,
                                                const float* __restrict__ sum,
                                                unsigned int* __restrict__ wq) {
    const float thr = 0.5f * (sum[0] * (1.0f / 16777216.0f));
    int tid = blockIdx.x * 256 + threadIdx.x;
    const float4* w4 = (const float4*)w;
    const int total4 = WCOUNT / 4;
    for (int i = tid; i < total4; i += 2048 * 256) {
        float4 v = w4[i];
        union { signed char c[4]; unsigned int u; } q;
        q.c[0] = v.x > thr ? 1 : (v.x < -thr ? -1 : 0);
        q.c[1] = v.y > thr ? 1 : (v.y < -thr ? -1 : 0);
        q.c[2] = v.z > thr ? 1 : (v.z < -thr ? -1 : 0);
        q.c[3] = v.w > thr ? 1 : (v.w < -thr ? -1 : 0);
        wq[i] = q.u;
    }
}

// ---------------- kernel 4: per-row activation quant -> int8 + scale ----------------
__global__ __launch_bounds__(256) void k_xquant(const float* __restrict__ x,
                                                signed char* __restrict__ xq,
                                                float* __restrict__ scale) {
    const int row = blockIdx.x;
    const int t = threadIdx.x;
    const float4* xr = (const float4*)(x + (size_t)row * K_DIM);
    float4 a = xr[t * 2];
    float4 b = xr[t * 2 + 1];
    float m = fmaxf(fmaxf(fmaxf(fabsf(a.x), fabsf(a.y)), fmaxf(fabsf(a.z), fabsf(a.w))),
                    fmaxf(fmaxf(fabsf(b.x), fabsf(b.y)), fmaxf(fabsf(b.z), fabsf(b.w))));
    #pragma unroll
    for (int off = 1; off < 64; off <<= 1) m = fmaxf(m, __shfl_xor(m, off));
    __shared__ float red[4];
    if ((t & 63) == 0) red[t >> 6] = m;
    __syncthreads();
    m = fmaxf(fmaxf(red[0], red[1]), fmaxf(red[2], red[3]));
    const float sc = fmaxf(m, 1e-5f);
    if (t == 0) scale[row] = sc;
    const float r = 127.0f / sc;
    float q[8] = {a.x, a.y, a.z, a.w, b.x, b.y, b.z, b.w};
    union { signed char c[8]; uint2 v; } pk;
    #pragma unroll
    for (int j = 0; j < 8; j++) {
        float v = rintf(q[j] * r);
        v = fminf(fmaxf(v, -127.0f), 127.0f);
        pk.c[j] = (signed char)v;
    }
    *(uint2*)(xq + (size_t)row * K_DIM + t * 8) = pk.v;
}

// ---------------- kernel 5: 256x256 i8 GEMM, derived-waits 8-phase ring ----------
// A = x_q [M][K] i8, B = w_q [N][K] i8, out[M][N] fp32 = relu(acc*coef)^2.
// 512 thr / 8 waves (2Mx4N), wave tile 128x64 = 4x2 tiles of 32x32x32 i8 MFMA.
// LDS 128 KiB: 2 buffers x (A 32K + B 32K). Swizzle: 16B slot s of row r holds
// chunk g = s ^ ((r>>1)&7) (inverse-swizzled source, linear GLDS dest, swizzled
// ds_read — rule 21; 0 conflicts measured R2-R7).
// DERIVED-WAITS ring (the m201/m218 property my R4-R7 rings lacked): all stages
// consolidated on the two read-free phases; gates vmcnt(8) leave exactly the
// just-issued 8 loads outstanding and force the PREVIOUS stage-phase's 8 -> every
// half-tile has 4 phases of flight before it is forced. Counted lgkmcnt(6) forces
// only the slice consumed now (just-issued slice flies under MFMA). Per iter
// (kt=2i in buf0, kt+1 in buf1), phases (per-wave op counts):
//  ph1: RD b0 s0+s1 (12)  LGKM6  MM(s0) BAR
//  ph2: RD b0 s2    (6)   LGKM6  MM(s1) BAR
//  ph3: RD b0 s3    (6)   LGKM6  MM(s2) BAR
//  ph4: STG buf0<-kt+2 (8) VMCNT8[forces kt+1] LGKM0 MM(s3) BAR
//  ph5-ph8: same on buf1; ph8 stages buf1<-kt+3, VMCNT8 forces kt+2.
// WAR: buf restage issues 1 barrier after its last read-issue phase (DMA data
// arrives >=300cy later). Peeled last iter: no stages, gates vmcnt(0) (no stall:
// all flights >=4 phases). Prologue stages kt0+kt1, drains to 8 (kt0 forced).
#define GLDS16(g, l)                                                                   \
    __builtin_amdgcn_global_load_lds((const __attribute__((address_space(1))) void*)(g), \
                                     (__attribute__((address_space(3))) void*)(l), 16, 0, 0)

#define AOFF(b, h) ((b) * 32768 + (h) * 16384)
#define BOFF(b, h) (65536 + (b) * 32768 + (h) * 16384)
#define BAR __builtin_amdgcn_s_barrier()
#define LGKM6 asm volatile("s_waitcnt lgkmcnt(6)" ::: "memory")
#define LGKM0 asm volatile("s_waitcnt lgkmcnt(0)" ::: "memory")
#define VMCNT8 asm volatile("s_waitcnt vmcnt(8)" ::: "memory")
#define VMCNT0 asm volatile("s_waitcnt vmcnt(0)" ::: "memory")

__global__ __launch_bounds__(512, 2) void k_gemm(const signed char* __restrict__ Aq,
                                                 const signed char* __restrict__ Bq,
                                                 const float* __restrict__ scale,
                                                 const float* __restrict__ sum,
                                                 float* __restrict__ out) {
    __shared__ signed char lds[131072];

    const int t = threadIdx.x;
    const int lane = t & 63;
    const int wid = t >> 6;        // 0..7
    const int wm = wid >> 2;       // 0..1  (M half: 128 rows)
    const int wn = wid & 3;        // 0..3  (N quarter: 64 cols)
    const int l31 = lane & 31;
    const int kg = lane >> 5;      // k-group for 32x32 operands

    // L2-aware mapping: XCD x owns brows [4x,4x+4); 4x4 supertiles sweep bcol.
    const int bid = blockIdx.x;
    const int xcd = bid & 7;
    const int s_ = bid >> 3;
    const int scol = s_ >> 4;
    const int w_ = s_ & 15;
    const int brow = xcd * 4 + (w_ >> 2);
    const int bcol = scol * 4 + (w_ & 3);

    // staging: thread t covers LDS chunk (row=t>>3, slot=t&7) of a 128-row half;
    // fetches global chunk g = slot ^ ((row>>1)&7) (inverse swizzle).
    const int g_ = ((t & 7) ^ ((t >> 4) & 7)) << 4;
    const size_t sa0 = (size_t)(t >> 3) * K_DIM + g_;
    const size_t sa1 = (size_t)(64 + (t >> 3)) * K_DIM + g_;
    const int dst0 = wid * 1024;          // + lane*16 implicit (wave-uniform base)
    const int dst1 = wid * 1024 + 8192;

    const signed char* Abase = Aq + (size_t)(brow * 256) * K_DIM;
    const signed char* Bbase = Bq + (size_t)(bcol * 256) * K_DIM;

#define STGH(gb, lo) do { GLDS16((gb) + sa0, lds + (lo) + dst0);                  \
                          GLDS16((gb) + sa1, lds + (lo) + dst1); } while (0)
#define STG_A(buf, kt) do { STGH(Abase + (size_t)(kt) * BK, AOFF(buf, 0));        \
        STGH(Abase + 128 * (size_t)K_DIM + (size_t)(kt) * BK, AOFF(buf, 1)); } while (0)
#define STG_B(buf, kt) do { STGH(Bbase + (size_t)(kt) * BK, BOFF(buf, 0));        \
        STGH(Bbase + 128 * (size_t)K_DIM + (size_t)(kt) * BK, BOFF(buf, 1)); } while (0)

    // ---- fragment reads (32x32x32): lane holds op[row=l31][k = kg*16 + 0..15];
    // k-chunk(16B) = ks*2 + kg, swizzled with rswz = ((l31>>1)&7).
    const int rswz = (l31 >> 1) & 7;
    const int ko0 = ((0 * 2 + kg) ^ rswz) << 4;
    const int ko1 = ((1 * 2 + kg) ^ rswz) << 4;
    const int ko2 = ((2 * 2 + kg) ^ rswz) << 4;
    const int ko3 = ((3 * 2 + kg) ^ rswz) << 4;
    const int aB0 = AOFF(0, wm) + l31 * 128;                        // + mt*4096 + ko
    const int aB1 = AOFF(1, wm) + l31 * 128;
    const int bB0 = BOFF(0, wn >> 1) + ((wn & 1) * 64 + l31) * 128; // + nt*4096 + ko
    const int bB1 = BOFF(1, wn >> 1) + ((wn & 1) * 64 + l31) * 128;

    i32x16 acc[4][2];
    #pragma unroll
    for (int m = 0; m < 4; m++)
        #pragma unroll
        for (int n = 0; n < 2; n++)
            acc[m][n] = (i32x16){0,0,0,0,0,0,0,0,0,0,0,0,0,0,0,0};
    i32x4 fA0[4], fB0[2], fA1[4], fB1[2];   // 2 fragment sets (even/odd slices)

#define RDS(FA, FB, ab, bb, ko) do {                                              \
        _Pragma("unroll") for (int m_ = 0; m_ < 4; m_++)                          \
            FA[m_] = *(const i32x4*)&lds[(ab) + m_ * 4096 + (ko)];                \
        _Pragma("unroll") for (int n_ = 0; n_ < 2; n_++)                          \
            FB[n_] = *(const i32x4*)&lds[(bb) + n_ * 4096 + (ko)]; } while (0)
#define MMX(FA, FB) do { __builtin_amdgcn_s_setprio(1);                           \
        _Pragma("unroll") for (int m_ = 0; m_ < 4; m_++)                          \
        _Pragma("unroll") for (int n_ = 0; n_ < 2; n_++)                          \
            acc[m_][n_] = __builtin_amdgcn_mfma_i32_32x32x32_i8(                  \
                FA[m_], FB[n_], acc[m_][n_], 0, 0, 0);                            \
        __builtin_amdgcn_s_setprio(0); } while (0)

    // ---- prologue: stage kt0 (buf0) + kt1 (buf1) = 16 loads; force kt0; BAR.
    STG_A(0, 0); STG_B(0, 0);
    STG_A(1, 1); STG_B(1, 1);
    VMCNT8;                    // kt0's 8 landed; kt1's 8 in flight (4-phase lead)
    BAR;

    #pragma unroll 1
    for (int i = 0; i < 8; i++) {
        const int kt = 2 * i;
        // ---- buf0 = kt ----
        // ph1
        RDS(fA0, fB0, aB0, bB0, ko0);
        RDS(fA1, fB1, aB0, bB0, ko1);
        LGKM6; MMX(fA0, fB0); BAR;
        // ph2
        RDS(fA0, fB0, aB0, bB0, ko2);
        LGKM6; MMX(fA1, fB1); BAR;
        // ph3
        RDS(fA1, fB1, aB0, bB0, ko3);
        LGKM6; MMX(fA0, fB0); BAR;
        // ph4: restage buf0 <- kt+2; gate buf1 (kt+1, staged 4 phases ago)
        if (i < 7) { STG_A(0, kt + 2); STG_B(0, kt + 2); VMCNT8; }
        else       { VMCNT0; }
        LGKM0; MMX(fA1, fB1); BAR;
        // ---- buf1 = kt+1 ----
        // ph5
        RDS(fA0, fB0, aB1, bB1, ko0);
        RDS(fA1, fB1, aB1, bB1, ko1);
        LGKM6; MMX(fA0, fB0); BAR;
        // ph6
        RDS(fA0, fB0, aB1, bB1, ko2);
        LGKM6; MMX(fA1, fB1); BAR;
        // ph7
        RDS(fA1, fB1, aB1, bB1, ko3);
        LGKM6; MMX(fA0, fB0); BAR;
        // ph8: restage buf1 <- kt+3; gate buf0 (kt+2, staged 4 phases ago)
        if (i < 7) { STG_A(1, kt + 3); STG_B(1, kt + 3); VMCNT8; }
        else       { VMCNT0; }
        LGKM0; MMX(fA1, fB1); BAR;
    }

    // ---- epilogue: out = (max(acc * w_scale / scale_row, 0))^2
    // 32x32 C/D: col = lane&31, row = (reg&3) + 8*(reg>>2) + 4*(lane>>5)
    const float wsc = sum[0] * (1.0f / 16777216.0f);
    const int rb = brow * 256 + wm * 128 + 4 * kg;
    const int cb = bcol * 256 + wn * 64 + l31;
    #pragma unroll
    for (int m = 0; m < 4; m++) {
        #pragma unroll
        for (int r = 0; r < 16; r++) {
            const int grow = rb + m * 32 + (r & 3) + 8 * (r >> 2);
            const float coef = wsc / scale[grow];
            #pragma unroll
            for (int n = 0; n < 2; n++) {
                float v = (float)acc[m][n][r] * coef;
                v = fmaxf(v, 0.0f);
                out[(size_t)grow * N_DIM + cb + n * 32] = v * v;
            }
        }
    }
#undef STGH
#undef STG_A
#undef STG_B
#undef RDS
#undef MMX
}

// ---------------- launch ----------------
extern "C" void kernel_launch(void* const* d_in, const int* in_sizes, int n_in,
                              void* d_out, int out_size, void* d_ws, size_t ws_size,
                              hipStream_t stream) {
    const float* x = (const float*)d_in[0];   // [4,2048,2048] fp32
    const float* w = (const float*)d_in[1];   // [8192,2048] fp32
    float* out = (float*)d_out;               // [4,2048,8192] fp32

    char* ws = (char*)d_ws;
    float* sum   = (float*)ws;
    float* part  = (float*)(ws + 256);
    float* scale = (float*)(ws + 16384);
    signed char* xq = (signed char*)(ws + 65536);
    signed char* wq = (signed char*)(ws + 65536 + 16777216);

    k_abs_partial<<<2048, 256, 0, stream>>>(w, part);
    k_abs_final<<<1, 256, 0, stream>>>(part, sum);
    k_wquant<<<2048, 256, 0, stream>>>(w, sum, (unsigned int*)wq);
    k_xquant<<<M_DIM, 256, 0, stream>>>(x, xq, scale);
    k_gemm<<<dim3(1024), 512, 0, stream>>>(xq, wq, scale, sum, out);
}

// Round 9
// 195.334 us; speedup vs baseline: 1.0429x; 1.0429x over previous
//
#include <hip/hip_runtime.h>
#include <hip/hip_bf16.h>

typedef __attribute__((ext_vector_type(4))) int i32x4;
typedef __attribute__((ext_vector_type(16))) int i32x16;

#define M_DIM 8192
#define N_DIM 8192
#define K_DIM 2048
#define WCOUNT (N_DIM * K_DIM)

// ---------------- kernel 1: per-block partial sums of |w| ----------------
__global__ __launch_bounds__(256) void k_abs_partial(const float* __restrict__ w,
                                                     float* __restrict__ part) {
    int tid = blockIdx.x * 256 + threadIdx.x;
    const float4* w4 = (const float4*)w;
    float s = 0.0f;
    const int total4 = WCOUNT / 4;
    for (int i = tid; i < total4; i += 2048 * 256) {
        float4 v = w4[i];
        s += fabsf(v.x) + fabsf(v.y) + fabsf(v.z) + fabsf(v.w);
    }
    #pragma unroll
    for (int off = 1; off < 64; off <<= 1) s += __shfl_xor(s, off);
    __shared__ float red[4];
    if ((threadIdx.x & 63) == 0) red[threadIdx.x >> 6] = s;
    __syncthreads();
    if (threadIdx.x == 0)
        part[blockIdx.x] = (red[0] + red[1]) + (red[2] + red[3]);
}

// ---------------- kernel 2: deterministic final reduce -> sum|w| ----------------
__global__ __launch_bounds__(256) void k_abs_final(const float* __restrict__ part,
                                                   float* __restrict__ sum) {
    int t = threadIdx.x;
    float s = 0.0f;
    #pragma unroll
    for (int i = 0; i < 8; i++) s += part[t + i * 256];
    #pragma unroll
    for (int off = 1; off < 64; off <<= 1) s += __shfl_xor(s, off);
    __shared__ float red[4];
    if ((t & 63) == 0) red[t >> 6] = s;
    __syncthreads();
    if (t == 0) sum[0] = (red[0] + red[1]) + (red[2] + red[3]);
}

// ---------------- kernel 3: ternary weight quant -> int8 {-1,0,1} ----------------
__global__ __launch_bounds__(256) void k_wquant(const float* __restrict__ w,
                                                const float* __restrict__ sum,
                                                unsigned int* __restrict__ wq) {
    const float thr = 0.5f * (sum[0] * (1.0f / 16777216.0f));
    int tid = blockIdx.x * 256 + threadIdx.x;
    const float4* w4 = (const float4*)w;
    const int total4 = WCOUNT / 4;
    for (int i = tid; i < total4; i += 2048 * 256) {
        float4 v = w4[i];
        union { signed char c[4]; unsigned int u; } q;
        q.c[0] = v.x > thr ? 1 : (v.x < -thr ? -1 : 0);
        q.c[1] = v.y > thr ? 1 : (v.y < -thr ? -1 : 0);
        q.c[2] = v.z > thr ? 1 : (v.z < -thr ? -1 : 0);
        q.c[3] = v.w > thr ? 1 : (v.w < -thr ? -1 : 0);
        wq[i] = q.u;
    }
}

// ---------------- kernel 4: per-row activation quant -> int8 + scale ----------------
__global__ __launch_bounds__(256) void k_xquant(const float* __restrict__ x,
                                                signed char* __restrict__ xq,
                                                float* __restrict__ scale) {
    const int row = blockIdx.x;
    const int t = threadIdx.x;
    const float4* xr = (const float4*)(x + (size_t)row * K_DIM);
    float4 a = xr[t * 2];
    float4 b = xr[t * 2 + 1];
    float m = fmaxf(fmaxf(fmaxf(fabsf(a.x), fabsf(a.y)), fmaxf(fabsf(a.z), fabsf(a.w))),
                    fmaxf(fmaxf(fabsf(b.x), fabsf(b.y)), fmaxf(fabsf(b.z), fabsf(b.w))));
    #pragma unroll
    for (int off = 1; off < 64; off <<= 1) m = fmaxf(m, __shfl_xor(m, off));
    __shared__ float red[4];
    if ((t & 63) == 0) red[t >> 6] = m;
    __syncthreads();
    m = fmaxf(fmaxf(red[0], red[1]), fmaxf(red[2], red[3]));
    const float sc = fmaxf(m, 1e-5f);
    if (t == 0) scale[row] = sc;
    const float r = 127.0f / sc;
    float q[8] = {a.x, a.y, a.z, a.w, b.x, b.y, b.z, b.w};
    union { signed char c[8]; uint2 v; } pk;
    #pragma unroll
    for (int j = 0; j < 8; j++) {
        float v = rintf(q[j] * r);
        v = fminf(fmaxf(v, -127.0f), 127.0f);
        pk.c[j] = (signed char)v;
    }
    *(uint2*)(xq + (size_t)row * K_DIM + t * 8) = pk.v;
}

// ---------------- kernel 4b: per-row epilogue coefficient ----------------
__global__ __launch_bounds__(256) void k_coef(const float* __restrict__ sum,
                                              const float* __restrict__ scale,
                                              float* __restrict__ coef) {
    const int i = blockIdx.x * 256 + threadIdx.x;
    coef[i] = (sum[0] * (1.0f / 16777216.0f)) / scale[i];
}

// ---------------- kernel 5: 128x256 i8 GEMM, 2 blocks/CU epilogue overlap -------
// A = x_q [M][K] i8, B = w_q [N][K] i8, out[M][N] fp32 = relu(acc*coef)^2.
// 512 thr / 8 waves (2Mx4N), wave out 64x64 = 2x2 of 32x32x32 i8 MFMA (acc 64).
// LDS 48 KiB = 2 buffers x (A[128][64] 8K + B[256][64] 16K) -> with
// __launch_bounds__(512,4): 2 BLOCKS/CU. Rationale: the 256-MB fp32 output makes
// each block's epilogue a ~40%-of-lifetime serial write burst (write-BW-bound);
// with 2 resident blocks one block's epilogue overlaps the other's K-loop
// (m114 mechanism) — the K-loop schedule itself proved non-binding (R4-R8 all
// ~same). Simple 2-barrier counted-prefetch loop; nontemporal epilogue stores
// (out never re-read; keeps L2 for A/B panels).
// Swizzle (R2-verified, 0 conflicts): 16B slot s of row r holds global chunk
// g = s ^ ((r>>1)&3); inverse-swizzled source, linear GLDS dest, swizzled read.
#define GLDS16(g, l)                                                                   \
    __builtin_amdgcn_global_load_lds((const __attribute__((address_space(1))) void*)(g), \
                                     (__attribute__((address_space(3))) void*)(l), 16, 0, 0)

#define BAR __builtin_amdgcn_s_barrier()
#define VMCNT3 asm volatile("s_waitcnt vmcnt(3)" ::: "memory")
#define VMCNT0 asm volatile("s_waitcnt vmcnt(0)" ::: "memory")
#define ABUF(b) ((b) * 24576)
#define BBUF(b) ((b) * 24576 + 8192)

__global__ __launch_bounds__(512, 4) void k_gemm(const signed char* __restrict__ Aq,
                                                 const signed char* __restrict__ Bq,
                                                 const float* __restrict__ coef,
                                                 float* __restrict__ out) {
    __shared__ signed char lds[49152];

    const int t = threadIdx.x;
    const int lane = t & 63;
    const int wid = t >> 6;        // 0..7
    const int wm = wid >> 2;       // 0..1  (M half: 64 rows)
    const int wn = wid & 3;        // 0..3  (N quarter: 64 cols)
    const int l31 = lane & 31;
    const int kg = lane >> 5;      // k-group for 32x32 operands

    // L2 mapping: XCD x owns brows [8x,8x+8) (A slice 2 MB resident); per XCD,
    // 8 groups of 4 bcols, each group sweeps 8 brows x 4 bcols.
    const int bid = blockIdx.x;
    const int xcd = bid & 7;
    const int idx = bid >> 3;                 // 0..255
    const int bcol = (idx >> 5) * 4 + (idx & 3);
    const int brow = xcd * 8 + ((idx >> 2) & 7);

    // staging: thread t covers LDS chunk t of each 8 KB region (row=t>>2,
    // slot=t&3); fetches global chunk g = (t&3)^((t>>3)&3) (inverse swizzle).
    const int g4 = ((t & 3) ^ ((t >> 3) & 3)) << 4;
    const int arow_s = t >> 2;                // 0..127
    const int dstc = wid * 1024;              // + lane*16 implicit (chunk c = t)

    const signed char* Abase = Aq + (size_t)(brow * 128) * K_DIM;
    const signed char* Bbase = Bq + (size_t)(bcol * 256) * K_DIM;

#define STG_K(buf, kt) do {                                                        \
        GLDS16(Abase + arow_s * K_DIM + (kt) * 64 + g4, lds + ABUF(buf) + dstc);   \
        GLDS16(Bbase + arow_s * K_DIM + (kt) * 64 + g4, lds + BBUF(buf) + dstc);   \
        GLDS16(Bbase + (128 + arow_s) * K_DIM + (kt) * 64 + g4,                    \
               lds + BBUF(buf) + 8192 + dstc); } while (0)

    // fragment reads: A row = wm*64 + mt*32 + l31; B row = wn*64 + nt*32 + l31;
    // slice ks chunk = ks*2+kg, swizzled slot ^= (l31>>1)&3.
    const int rs = (l31 >> 1) & 3;
    const int ko0 = ((0 + kg) ^ rs) << 4;     // slice 0
    const int ko1 = ((2 + kg) ^ rs) << 4;     // slice 1
    const int aoff = (wm * 64 + l31) * 64;    // + mt*2048 + ko + ABUF
    const int boff = 8192 + (wn * 64 + l31) * 64;  // + nt*2048 + ko + buf*24576

    i32x16 acc00 = (i32x16){0,0,0,0,0,0,0,0,0,0,0,0,0,0,0,0};
    i32x16 acc01 = acc00, acc10 = acc00, acc11 = acc00;

#define KTILE(buf) do {                                                            \
        const int ab = (buf) * 24576 + aoff;                                       \
        const int bb = (buf) * 24576 + boff;                                       \
        i32x4 a00 = *(const i32x4*)&lds[ab + ko0];                                 \
        i32x4 a10 = *(const i32x4*)&lds[ab + 2048 + ko0];                          \
        i32x4 b00 = *(const i32x4*)&lds[bb + ko0];                                 \
        i32x4 b10 = *(const i32x4*)&lds[bb + 2048 + ko0];                          \
        i32x4 a01 = *(const i32x4*)&lds[ab + ko1];                                 \
        i32x4 a11 = *(const i32x4*)&lds[ab + 2048 + ko1];                          \
        i32x4 b01 = *(const i32x4*)&lds[bb + ko1];                                 \
        i32x4 b11 = *(const i32x4*)&lds[bb + 2048 + ko1];                          \
        __builtin_amdgcn_s_setprio(1);                                             \
        acc00 = __builtin_amdgcn_mfma_i32_32x32x32_i8(a00, b00, acc00, 0, 0, 0);   \
        acc01 = __builtin_amdgcn_mfma_i32_32x32x32_i8(a00, b10, acc01, 0, 0, 0);   \
        acc10 = __builtin_amdgcn_mfma_i32_32x32x32_i8(a10, b00, acc10, 0, 0, 0);   \
        acc11 = __builtin_amdgcn_mfma_i32_32x32x32_i8(a10, b10, acc11, 0, 0, 0);   \
        acc00 = __builtin_amdgcn_mfma_i32_32x32x32_i8(a01, b01, acc00, 0, 0, 0);   \
        acc01 = __builtin_amdgcn_mfma_i32_32x32x32_i8(a01, b11, acc01, 0, 0, 0);   \
        acc10 = __builtin_amdgcn_mfma_i32_32x32x32_i8(a11, b01, acc10, 0, 0, 0);   \
        acc11 = __builtin_amdgcn_mfma_i32_32x32x32_i8(a11, b11, acc11, 0, 0, 0);   \
        __builtin_amdgcn_s_setprio(0); } while (0)

    // ---- prologue: kt0 -> buf0, kt1 -> buf1 (3 loads each); force buf0.
    STG_K(0, 0);
    STG_K(1, 1);
    VMCNT3;
    BAR;

    // ---- main loop: 32 K-tiles, dbuf, counted vmcnt(3) prefetch gates.
    #pragma unroll 1
    for (int i = 0; i < 16; i++) {
        const int kt = 2 * i;
        KTILE(0);                               // reads buf0 (kt), lgkm auto
        BAR;                                    // all reads of buf0 done
        if (i < 15) { STG_K(0, kt + 2); VMCNT3; }   // restage buf0; force kt+1
        else        { VMCNT0; }                     // force kt31 (last)
        BAR;
        KTILE(1);                               // reads buf1 (kt+1)
        if (i < 15) {
            BAR;
            STG_K(1, kt + 3); VMCNT3;           // restage buf1; force kt+2
            BAR;
        }
    }

    // ---- epilogue: out = (max(acc * coef[row], 0))^2, nontemporal stores.
    // 32x32 C/D: col = lane&31, row = (r&3) + 8*(r>>2) + 4*(lane>>5)
    const int rb = brow * 128 + wm * 64 + 4 * kg;
    const int cb = bcol * 256 + wn * 64 + l31;
    #pragma unroll
    for (int mt = 0; mt < 2; mt++) {
        const i32x16 ac0 = mt ? acc10 : acc00;
        const i32x16 ac1 = mt ? acc11 : acc01;
        #pragma unroll
        for (int r = 0; r < 16; r++) {
            const int grow = rb + mt * 32 + (r & 3) + 8 * (r >> 2);
            const float c = coef[grow];
            float v0 = (float)ac0[r] * c; v0 = fmaxf(v0, 0.0f);
            float v1 = (float)ac1[r] * c; v1 = fmaxf(v1, 0.0f);
            __builtin_nontemporal_store(v0 * v0, &out[(size_t)grow * N_DIM + cb]);
            __builtin_nontemporal_store(v1 * v1, &out[(size_t)grow * N_DIM + cb + 32]);
        }
    }
#undef STG_K
#undef KTILE
}

// ---------------- launch ----------------
extern "C" void kernel_launch(void* const* d_in, const int* in_sizes, int n_in,
                              void* d_out, int out_size, void* d_ws, size_t ws_size,
                              hipStream_t stream) {
    const float* x = (const float*)d_in[0];   // [4,2048,2048] fp32
    const float* w = (const float*)d_in[1];   // [8192,2048] fp32
    float* out = (float*)d_out;               // [4,2048,8192] fp32

    char* ws = (char*)d_ws;
    float* sum   = (float*)ws;                          // 1 float
    float* part  = (float*)(ws + 256);                  // 2048 floats
    float* scale = (float*)(ws + 16384);                // 8192 floats
    float* coef  = (float*)(ws + 49152);                // 8192 floats
    signed char* xq = (signed char*)(ws + 131072);              // 16.78 MB i8
    signed char* wq = (signed char*)(ws + 131072 + 16777216);   // 16.78 MB i8

    k_abs_partial<<<2048, 256, 0, stream>>>(w, part);
    k_abs_final<<<1, 256, 0, stream>>>(part, sum);
    k_wquant<<<2048, 256, 0, stream>>>(w, sum, (unsigned int*)wq);
    k_xquant<<<M_DIM, 256, 0, stream>>>(x, xq, scale);
    k_coef<<<32, 256, 0, stream>>>(sum, scale, coef);
    k_gemm<<<dim3(2048), 512, 0, stream>>>(xq, wq, coef, out);
}

// Round 10
// 194.359 us; speedup vs baseline: 1.0481x; 1.0050x over previous
//
#include <hip/hip_runtime.h>
#include <hip/hip_bf16.h>

typedef __attribute__((ext_vector_type(4))) int i32x4;
typedef __attribute__((ext_vector_type(16))) int i32x16;

#define M_DIM 8192
#define N_DIM 8192
#define K_DIM 2048
#define WCOUNT (N_DIM * K_DIM)

// ---------------- kernel 1: per-block partial sums of |w| ----------------
__global__ __launch_bounds__(256) void k_abs_partial(const float* __restrict__ w,
                                                     float* __restrict__ part) {
    int tid = blockIdx.x * 256 + threadIdx.x;
    const float4* w4 = (const float4*)w;
    float s = 0.0f;
    const int total4 = WCOUNT / 4;
    for (int i = tid; i < total4; i += 2048 * 256) {
        float4 v = w4[i];
        s += fabsf(v.x) + fabsf(v.y) + fabsf(v.z) + fabsf(v.w);
    }
    #pragma unroll
    for (int off = 1; off < 64; off <<= 1) s += __shfl_xor(s, off);
    __shared__ float red[4];
    if ((threadIdx.x & 63) == 0) red[threadIdx.x >> 6] = s;
    __syncthreads();
    if (threadIdx.x == 0)
        part[blockIdx.x] = (red[0] + red[1]) + (red[2] + red[3]);
}

// ---------------- kernel 2: deterministic final reduce -> sum|w| ----------------
__global__ __launch_bounds__(256) void k_abs_final(const float* __restrict__ part,
                                                   float* __restrict__ sum) {
    int t = threadIdx.x;
    float s = 0.0f;
    #pragma unroll
    for (int i = 0; i < 8; i++) s += part[t + i * 256];
    #pragma unroll
    for (int off = 1; off < 64; off <<= 1) s += __shfl_xor(s, off);
    __shared__ float red[4];
    if ((t & 63) == 0) red[t >> 6] = s;
    __syncthreads();
    if (t == 0) sum[0] = (red[0] + red[1]) + (red[2] + red[3]);
}

// ---------------- kernel 3: ternary weight quant -> int8 {-1,0,1} ----------------
__global__ __launch_bounds__(256) void k_wquant(const float* __restrict__ w,
                                                const float* __restrict__ sum,
                                                unsigned int* __restrict__ wq) {
    const float thr = 0.5f * (sum[0] * (1.0f / 16777216.0f));
    int tid = blockIdx.x * 256 + threadIdx.x;
    const float4* w4 = (const float4*)w;
    const int total4 = WCOUNT / 4;
    for (int i = tid; i < total4; i += 2048 * 256) {
        float4 v = w4[i];
        union { signed char c[4]; unsigned int u; } q;
        q.c[0] = v.x > thr ? 1 : (v.x < -thr ? -1 : 0);
        q.c[1] = v.y > thr ? 1 : (v.y < -thr ? -1 : 0);
        q.c[2] = v.z > thr ? 1 : (v.z < -thr ? -1 : 0);
        q.c[3] = v.w > thr ? 1 : (v.w < -thr ? -1 : 0);
        wq[i] = q.u;
    }
}

// ---------------- kernel 4: per-row activation quant -> int8 + scale ----------------
__global__ __launch_bounds__(256) void k_xquant(const float* __restrict__ x,
                                                signed char* __restrict__ xq,
                                                float* __restrict__ scale) {
    const int row = blockIdx.x;
    const int t = threadIdx.x;
    const float4* xr = (const float4*)(x + (size_t)row * K_DIM);
    float4 a = xr[t * 2];
    float4 b = xr[t * 2 + 1];
    float m = fmaxf(fmaxf(fmaxf(fabsf(a.x), fabsf(a.y)), fmaxf(fabsf(a.z), fabsf(a.w))),
                    fmaxf(fmaxf(fabsf(b.x), fabsf(b.y)), fmaxf(fabsf(b.z), fabsf(b.w))));
    #pragma unroll
    for (int off = 1; off < 64; off <<= 1) m = fmaxf(m, __shfl_xor(m, off));
    __shared__ float red[4];
    if ((t & 63) == 0) red[t >> 6] = m;
    __syncthreads();
    m = fmaxf(fmaxf(red[0], red[1]), fmaxf(red[2], red[3]));
    const float sc = fmaxf(m, 1e-5f);
    if (t == 0) scale[row] = sc;
    const float r = 127.0f / sc;
    float q[8] = {a.x, a.y, a.z, a.w, b.x, b.y, b.z, b.w};
    union { signed char c[8]; uint2 v; } pk;
    #pragma unroll
    for (int j = 0; j < 8; j++) {
        float v = rintf(q[j] * r);
        v = fminf(fmaxf(v, -127.0f), 127.0f);
        pk.c[j] = (signed char)v;
    }
    *(uint2*)(xq + (size_t)row * K_DIM + t * 8) = pk.v;
}

// ---------------- kernel 4b: per-row epilogue coefficient ----------------
__global__ __launch_bounds__(256) void k_coef(const float* __restrict__ sum,
                                              const float* __restrict__ scale,
                                              float* __restrict__ coef) {
    const int i = blockIdx.x * 256 + threadIdx.x;
    coef[i] = (sum[0] * (1.0f / 16777216.0f)) / scale[i];
}

// ---------------- kernel 5: 128x256 i8 GEMM, 2 blocks/CU, paired-row LDS -------
// A = x_q [M][K] i8, B = w_q [N][K] i8, out[M][N] fp32 = relu(acc*coef)^2.
// 512 thr / 8 waves (2Mx4N), wave out 64x64 = 2x2 of 32x32x32 i8 (acc 64 regs).
// LDS 48 KiB, __launch_bounds__(512,4) -> 2 blocks/CU: one block's epilogue
// (256 KB fp32 writes) overlaps the other's K-loop (R9: +12%, occupancy 39%).
// PAIRED-ROW LDS LAYOUT (fixes R9's 1.68e7 bank conflicts): each 128-B LDS line
// holds two 64-B matrix rows (2g, 2g+1). Slot s = (row&1)*4 + chunk stored at
// s' = s ^ (g&7) (involution). Read: any 8 consecutive lanes hit all 8 slots =
// all 32 banks exactly once (stronger than R8's measured-zero pattern).
// Rule 21: linear GLDS dest (byte t*16) + inverse-mapped global source + same
// swizzle on ds_read.
#define GLDS16(g, l)                                                                   \
    __builtin_amdgcn_global_load_lds((const __attribute__((address_space(1))) void*)(g), \
                                     (__attribute__((address_space(3))) void*)(l), 16, 0, 0)

#define BAR __builtin_amdgcn_s_barrier()
#define VMCNT3 asm volatile("s_waitcnt vmcnt(3)" ::: "memory")
#define VMCNT0 asm volatile("s_waitcnt vmcnt(0)" ::: "memory")
#define ABUF(b) ((b) * 24576)
#define BBUF(b) ((b) * 24576 + 8192)

__global__ __launch_bounds__(512, 4) void k_gemm(const signed char* __restrict__ Aq,
                                                 const signed char* __restrict__ Bq,
                                                 const float* __restrict__ coef,
                                                 float* __restrict__ out) {
    __shared__ signed char lds[49152];

    const int t = threadIdx.x;
    const int lane = t & 63;
    const int wid = t >> 6;        // 0..7
    const int wm = wid >> 2;       // 0..1  (M half: 64 rows)
    const int wn = wid & 3;        // 0..3  (N quarter: 64 cols)
    const int l31 = lane & 31;
    const int kg = lane >> 5;      // k-group for 32x32 operands

    // L2 mapping: XCD x owns brows [8x,8x+8) (A slice 2 MB resident); per XCD,
    // 8 groups of 4 bcols, each group sweeps 8 brows x 4 bcols.
    const int bid = blockIdx.x;
    const int xcd = bid & 7;
    const int idx = bid >> 3;                 // 0..255
    const int bcol = (idx >> 5) * 4 + (idx & 3);
    const int brow = xcd * 8 + ((idx >> 2) & 7);

    // ---- staging geometry (paired-row layout). Thread t -> LDS byte t*16
    // (linear: line g = t>>3, slot s' = t&7). Content of (g, s'): s = s'^(g&7),
    // row = 2g + (s>>2), chunk = s&3.
    const int s_map = (t & 7) ^ ((t >> 3) & 7);
    const int srow = 2 * (t >> 3) + (s_map >> 2);          // 0..127
    const size_t sa = (size_t)srow * K_DIM + (s_map & 3) * 16;  // + kt*64
    const int dstc = wid * 1024;              // + lane*16 implicit (byte t*16)

    const signed char* Abase = Aq + (size_t)(brow * 128) * K_DIM;
    const signed char* Bbase = Bq + (size_t)(bcol * 256) * K_DIM;

#define STG_K(buf, kt) do {                                                        \
        GLDS16(Abase + sa + (kt) * 64, lds + ABUF(buf) + dstc);                    \
        GLDS16(Bbase + sa + (kt) * 64, lds + BBUF(buf) + dstc);                    \
        GLDS16(Bbase + 128 * (size_t)K_DIM + sa + (kt) * 64,                       \
               lds + BBUF(buf) + 8192 + dstc); } while (0)

    // ---- fragment reads: matrix row r = R0 + l31 (R0 mult of 32), chunk
    // c = ks*2 + kg. byte = R0*64 + (l31>>1)*128 + (((l31&1)*4+c)^((l31>>1)&7))*16.
    const int sl = l31 >> 1;
    const int lp4 = (l31 & 1) * 4;
    const int ko0 = ((lp4 | kg) ^ (sl & 7)) << 4;          // slice 0 (c = kg)
    const int ko1 = ((lp4 | (2 + kg)) ^ (sl & 7)) << 4;    // slice 1 (c = 2+kg)
    const int aoff = wm * 4096 + sl * 128;          // + mt*2048 + ko + ABUF
    const int boff = 8192 + wn * 4096 + sl * 128;   // + nt*2048 + ko + buf*24576

    i32x16 acc00 = (i32x16){0,0,0,0,0,0,0,0,0,0,0,0,0,0,0,0};
    i32x16 acc01 = acc00, acc10 = acc00, acc11 = acc00;

#define KTILE(buf) do {                                                            \
        const int ab = (buf) * 24576 + aoff;                                       \
        const int bb = (buf) * 24576 + boff;                                       \
        i32x4 a00 = *(const i32x4*)&lds[ab + ko0];                                 \
        i32x4 a10 = *(const i32x4*)&lds[ab + 2048 + ko0];                          \
        i32x4 b00 = *(const i32x4*)&lds[bb + ko0];                                 \
        i32x4 b10 = *(const i32x4*)&lds[bb + 2048 + ko0];                          \
        i32x4 a01 = *(const i32x4*)&lds[ab + ko1];                                 \
        i32x4 a11 = *(const i32x4*)&lds[ab + 2048 + ko1];                          \
        i32x4 b01 = *(const i32x4*)&lds[bb + ko1];                                 \
        i32x4 b11 = *(const i32x4*)&lds[bb + 2048 + ko1];                          \
        __builtin_amdgcn_s_setprio(1);                                             \
        acc00 = __builtin_amdgcn_mfma_i32_32x32x32_i8(a00, b00, acc00, 0, 0, 0);   \
        acc01 = __builtin_amdgcn_mfma_i32_32x32x32_i8(a00, b10, acc01, 0, 0, 0);   \
        acc10 = __builtin_amdgcn_mfma_i32_32x32x32_i8(a10, b00, acc10, 0, 0, 0);   \
        acc11 = __builtin_amdgcn_mfma_i32_32x32x32_i8(a10, b10, acc11, 0, 0, 0);   \
        acc00 = __builtin_amdgcn_mfma_i32_32x32x32_i8(a01, b01, acc00, 0, 0, 0);   \
        acc01 = __builtin_amdgcn_mfma_i32_32x32x32_i8(a01, b11, acc01, 0, 0, 0);   \
        acc10 = __builtin_amdgcn_mfma_i32_32x32x32_i8(a11, b01, acc10, 0, 0, 0);   \
        acc11 = __builtin_amdgcn_mfma_i32_32x32x32_i8(a11, b11, acc11, 0, 0, 0);   \
        __builtin_amdgcn_s_setprio(0); } while (0)

    // ---- prologue: kt0 -> buf0, kt1 -> buf1 (3 loads each); force buf0.
    STG_K(0, 0);
    STG_K(1, 1);
    VMCNT3;
    BAR;

    // ---- main loop: 32 K-tiles, dbuf, counted vmcnt(3) prefetch gates.
    #pragma unroll 1
    for (int i = 0; i < 16; i++) {
        const int kt = 2 * i;
        KTILE(0);                               // reads buf0 (kt), lgkm auto
        BAR;                                    // all reads of buf0 done
        if (i < 15) { STG_K(0, kt + 2); VMCNT3; }   // restage buf0; force kt+1
        else        { VMCNT0; }                     // force kt31 (last)
        BAR;
        KTILE(1);                               // reads buf1 (kt+1)
        if (i < 15) {
            BAR;
            STG_K(1, kt + 3); VMCNT3;           // restage buf1; force kt+2
            BAR;
        }
    }

    // ---- epilogue: out = (max(acc * coef[row], 0))^2, nontemporal stores.
    // 32x32 C/D: col = lane&31, row = (r&3) + 8*(r>>2) + 4*(lane>>5)
    const int rb = brow * 128 + wm * 64 + 4 * kg;
    const int cb = bcol * 256 + wn * 64 + l31;
    #pragma unroll
    for (int mt = 0; mt < 2; mt++) {
        const i32x16 ac0 = mt ? acc10 : acc00;
        const i32x16 ac1 = mt ? acc11 : acc01;
        #pragma unroll
        for (int r = 0; r < 16; r++) {
            const int grow = rb + mt * 32 + (r & 3) + 8 * (r >> 2);
            const float c = coef[grow];
            float v0 = (float)ac0[r] * c; v0 = fmaxf(v0, 0.0f);
            float v1 = (float)ac1[r] * c; v1 = fmaxf(v1, 0.0f);
            __builtin_nontemporal_store(v0 * v0, &out[(size_t)grow * N_DIM + cb]);
            __builtin_nontemporal_store(v1 * v1, &out[(size_t)grow * N_DIM + cb + 32]);
        }
    }
#undef STG_K
#undef KTILE
}

// ---------------- launch ----------------
extern "C" void kernel_launch(void* const* d_in, const int* in_sizes, int n_in,
                              void* d_out, int out_size, void* d_ws, size_t ws_size,
                              hipStream_t stream) {
    const float* x = (const float*)d_in[0];   // [4,2048,2048] fp32
    const float* w = (const float*)d_in[1];   // [8192,2048] fp32
    float* out = (float*)d_out;               // [4,2048,8192] fp32

    char* ws = (char*)d_ws;
    float* sum   = (float*)ws;                          // 1 float
    float* part  = (float*)(ws + 256);                  // 2048 floats
    float* scale = (float*)(ws + 16384);                // 8192 floats
    float* coef  = (float*)(ws + 49152);                // 8192 floats
    signed char* xq = (signed char*)(ws + 131072);              // 16.78 MB i8
    signed char* wq = (signed char*)(ws + 131072 + 16777216);   // 16.78 MB i8

    k_abs_partial<<<2048, 256, 0, stream>>>(w, part);
    k_abs_final<<<1, 256, 0, stream>>>(part, sum);
    k_wquant<<<2048, 256, 0, stream>>>(w, sum, (unsigned int*)wq);
    k_xquant<<<M_DIM, 256, 0, stream>>>(x, xq, scale);
    k_coef<<<32, 256, 0, stream>>>(sum, scale, coef);
    k_gemm<<<dim3(2048), 512, 0, stream>>>(xq, wq, coef, out);
}